// Round 4
// baseline (141.010 us; speedup 1.0000x reference)
//
#include <hip/hip_runtime.h>

// SupNet pair-distance head, v3: persistent 1-wave blocks, W2-in-registers.
//   rp[j][c] = z[j]·W1[c,:128] + b1[c]   (c < 256)
//   cp[i][c] = z[i]·W1[c,128:]
//   h[m][c]  = relu(rp[j(m)][c] + cp[i(m)][c])          (bf16)
//   h2[n][m] = relu( W2[n][:]·h[m][:] + b2[n] )         (b2 folded as K-ext)
//   out[m][o]= Wf[o][:]·h2[:][m] + bf[o]
//
// MFMA 32x32x16 bf16, A = W2 (n-channels), B = h (pairs). One wave per block,
// 4 blocks/CU, ~460 VGPRs, no barriers. Grid = 24 jb-groups x 43 waves;
// each wave stages its rp tile exactly once.

typedef __attribute__((ext_vector_type(8)))  __bf16       bf16x8;
typedef __attribute__((ext_vector_type(2)))  float        f32x2;
typedef __attribute__((ext_vector_type(4)))  float        f32x4;
typedef __attribute__((ext_vector_type(16))) float        f32x16;
typedef __attribute__((ext_vector_type(4)))  unsigned int u32x4;

#define NCELL 768
#define DIM   128
#define C1    256
#define C2    128
#define KP    272      // 256 + 16 pad; col 256 = b2, 257..271 = 0
#define NKS   17       // 16 real k-steps + 1 bias step
#define WPG   43       // waves per jb-group (42x9 + 1x6 = 384 i2-jobs)

// LDS map (bytes): rp [32 rows][1040] = 33280 | cp [2][1024] = 2048 | wf 1024
#define RP_OFF 0
#define RP_STR 1040
#define CP_OFF 33280
#define WF_OFF 35328
#define LDS_SZ 36352

// ---------------------------------------------------------------- pk helpers
static __device__ __forceinline__ f32x2 pk_add(f32x2 a, f32x2 b) {
    f32x2 d; asm("v_pk_add_f32 %0, %1, %2" : "=v"(d) : "v"(a), "v"(b)); return d;
}
// NOTE: no v_pk_max_f32 on gfx950 — scalar v_max_f32 per component.
static __device__ __forceinline__ f32x2 relu2(f32x2 a) {
    f32x2 d; d[0] = fmaxf(a[0], 0.f); d[1] = fmaxf(a[1], 0.f); return d;
}
static __device__ __forceinline__ unsigned cvtpk(float lo, float hi) {
    unsigned d; asm("v_cvt_pk_bf16_f32 %0, %1, %2" : "=v"(d) : "v"(lo), "v"(hi)); return d;
}
static __device__ __forceinline__ f32x2 lo2(f32x4 v) { return __builtin_shufflevector(v, v, 0, 1); }
static __device__ __forceinline__ f32x2 hi2(f32x4 v) { return __builtin_shufflevector(v, v, 2, 3); }

// ---------------------------------------------------------------- fused prep
// blocks 0..767: rp/cp row j; blocks 768..903: W2 -> bf16 padded (b2 col)
__global__ __launch_bounds__(256) void prep_all(const float* __restrict__ z,
                                                const float* __restrict__ W1,
                                                const float* __restrict__ b1,
                                                const float* __restrict__ W2,
                                                const float* __restrict__ b2,
                                                float* __restrict__ rp,
                                                float* __restrict__ cp,
                                                __bf16* __restrict__ w2p) {
    if (blockIdx.x < NCELL) {
        const int j = blockIdx.x;
        const int o = threadIdx.x;
        __shared__ float zl[DIM];
        if (o < DIM) zl[o] = z[(size_t)j * DIM + o];
        __syncthreads();
        const f32x4* w4 = (const f32x4*)(W1 + (size_t)o * (2 * DIM));
        const f32x4* z4 = (const f32x4*)zl;
        float a1 = 0.f, a2 = 0.f;
#pragma unroll 8
        for (int d4 = 0; d4 < DIM / 4; ++d4) {
            f32x4 zv = z4[d4], wa = w4[d4], wb = w4[DIM / 4 + d4];
#pragma unroll
            for (int e = 0; e < 4; ++e) {
                a1 = fmaf(zv[e], wa[e], a1);
                a2 = fmaf(zv[e], wb[e], a2);
            }
        }
        rp[(size_t)j * C1 + o] = a1 + b1[o];
        cp[(size_t)j * C1 + o] = a2;
    } else {
        const int t = (blockIdx.x - NCELL) * 256 + threadIdx.x;  // 0..34815
        const int row = t / KP;
        const int col = t - row * KP;
        float v = (col < C1) ? W2[row * C1 + col] : (col == C1 ? b2[row] : 0.f);
        w2p[t] = (__bf16)v;
    }
}

// ---------------------------------------------------------------- main kernel
__global__ __launch_bounds__(64, 1) void pair_head(const float* __restrict__ rp,
                                                   const float* __restrict__ cp,
                                                   const __bf16* __restrict__ w2p,
                                                   const float* __restrict__ Wf,
                                                   const float* __restrict__ bfv,
                                                   float* __restrict__ out) {
    __shared__ char smem[LDS_SZ];
    const int l  = threadIdx.x;
    const int ln = l & 31;
    const int kh = l >> 5;
    const int w  = blockIdx.x;        // 0..1031
    const int jb = w / WPG;           // jb-group, 0..23 (uniform per wave)
    const int s  = w - jb * WPG;      // slot in group, 0..42
    const int base_i2 = s * 9;
    const int count = (384 - base_i2 < 9) ? (384 - base_i2) : 9;

    // ---- stage rp j-tile (32 rows x 256 f32, +16B row pad). FULL tile.
#pragma unroll 16
    for (int c = l; c < 2048; c += 64) {
        int row = c >> 6, cc = c & 63;       // 64 x 16B chunks per row
        f32x4 v = *(const f32x4*)(rp + (size_t)(jb * 32 + row) * C1 + cc * 4);
        *(f32x4*)(smem + RP_OFF + row * RP_STR + cc * 16) = v;
    }

    // ---- Wf permuted table: [kh][r][ng][o] f32 (matches D-layout rows)
#pragma unroll
    for (int t = 0; t < 4; ++t) {
        int idx = l * 4 + t;                       // 0..255
        int okh = idx >> 7, r = (idx >> 3) & 15, ng = (idx >> 1) & 3, o = idx & 1;
        int n = ng * 32 + (r & 3) + 8 * ((r >> 2) & 3) + 4 * okh;
        *(float*)(smem + WF_OFF + idx * 4) = Wf[o * C2 + n];
    }

    // ---- W2 fragments (A-operand), all of W2 + b2 column, in registers
    bf16x8 w2f[4][NKS];
#pragma unroll
    for (int ng = 0; ng < 4; ++ng)
#pragma unroll
        for (int ks = 0; ks < NKS; ++ks)
            w2f[ng][ks] = *(const bf16x8*)(w2p + (size_t)(ng * 32 + ln) * KP + ks * 16 + kh * 8);

    // ones B-frag for the bias k-step: B[k][m] = (k==256)
    bf16x8 onesf = (bf16x8)(__bf16)0.0f;
    if (kh == 0) onesf[0] = (__bf16)1.0f;

    const float bf0 = bfv[0], bf1 = bfv[1];

    // ---- cp register double-buffer: prefetch job 0
    f32x4 cpr0, cpr1;
    {
        const float* src = cp + (size_t)(base_i2 * 2 + kh) * C1 + ln * 8;
        cpr0 = *(const f32x4*)(src);
        cpr1 = *(const f32x4*)(src + 4);
    }

    for (int t = 0; t < count; ++t) {
        const int i2 = base_i2 + t;

        // ---- write current cp rows to LDS (slot kh <- row i2*2+kh)
        *(f32x4*)(smem + CP_OFF + kh * 1024 + ln * 32)      = cpr0;
        *(f32x4*)(smem + CP_OFF + kh * 1024 + ln * 32 + 16) = cpr1;

        // ---- prefetch next job's cp (latency hides under K-loop)
        f32x4 cpn0, cpn1;
        if (t + 1 < count) {
            const float* src = cp + (size_t)((i2 + 1) * 2 + kh) * C1 + ln * 8;
            cpn0 = *(const f32x4*)(src);
            cpn1 = *(const f32x4*)(src + 4);
        }

        f32x16 acc[2][4];
#pragma unroll
        for (int g = 0; g < 2; ++g)
#pragma unroll
            for (int ng = 0; ng < 4; ++ng)
                acc[g][ng] = (f32x16)0.f;

        // ---- K loop: 16 real steps + bias step
#pragma unroll
        for (int ks = 0; ks < NKS; ++ks) {
            bf16x8 hb[2];
            if (ks < 16) {
                const char* rb = smem + RP_OFF + ln * RP_STR + ks * 64 + kh * 32;
                f32x4 r0 = *(const f32x4*)(rb);
                f32x4 r1 = *(const f32x4*)(rb + 16);
#pragma unroll
                for (int g = 0; g < 2; ++g) {
                    const char* cb = smem + CP_OFF + g * 1024 + ks * 64 + kh * 32;
                    f32x4 c0 = *(const f32x4*)(cb);
                    f32x4 c1 = *(const f32x4*)(cb + 16);
                    f32x2 s0 = relu2(pk_add(lo2(r0), lo2(c0)));
                    f32x2 s1 = relu2(pk_add(hi2(r0), hi2(c0)));
                    f32x2 s2 = relu2(pk_add(lo2(r1), lo2(c1)));
                    f32x2 s3 = relu2(pk_add(hi2(r1), hi2(c1)));
                    u32x4 hw;
                    hw[0] = cvtpk(s0[0], s0[1]);
                    hw[1] = cvtpk(s1[0], s1[1]);
                    hw[2] = cvtpk(s2[0], s2[1]);
                    hw[3] = cvtpk(s3[0], s3[1]);
                    hb[g] = __builtin_bit_cast(bf16x8, hw);
                }
            } else {
                hb[0] = onesf;
                hb[1] = onesf;
            }
#pragma unroll
            for (int g = 0; g < 2; ++g)
#pragma unroll
                for (int ng = 0; ng < 4; ++ng)
                    acc[g][ng] = __builtin_amdgcn_mfma_f32_32x32x16_bf16(
                        w2f[ng][ks], hb[g], acc[g][ng], 0, 0, 0);
        }

        // ---- epilogue: relu + Wf-dot (b2 already in acc via bias step)
        float p00 = 0.f, p01 = 0.f, p10 = 0.f, p11 = 0.f;  // [g][o]
#pragma unroll
        for (int r = 0; r < 16; ++r) {
            const float* wfp = (const float*)(smem + WF_OFF + kh * 512 + r * 32);
            f32x4 wa = *(const f32x4*)(wfp);      // ng0:{o0,o1} ng1:{o0,o1}
            f32x4 wb = *(const f32x4*)(wfp + 4);  // ng2,ng3
            {
                float h0 = fmaxf(acc[0][0][r], 0.f), h1 = fmaxf(acc[0][1][r], 0.f);
                float h2 = fmaxf(acc[0][2][r], 0.f), h3 = fmaxf(acc[0][3][r], 0.f);
                p00 = fmaf(wa[0], h0, p00); p01 = fmaf(wa[1], h0, p01);
                p00 = fmaf(wa[2], h1, p00); p01 = fmaf(wa[3], h1, p01);
                p00 = fmaf(wb[0], h2, p00); p01 = fmaf(wb[1], h2, p01);
                p00 = fmaf(wb[2], h3, p00); p01 = fmaf(wb[3], h3, p01);
            }
            {
                float h0 = fmaxf(acc[1][0][r], 0.f), h1 = fmaxf(acc[1][1][r], 0.f);
                float h2 = fmaxf(acc[1][2][r], 0.f), h3 = fmaxf(acc[1][3][r], 0.f);
                p10 = fmaf(wa[0], h0, p10); p11 = fmaf(wa[1], h0, p11);
                p10 = fmaf(wa[2], h1, p10); p11 = fmaf(wa[3], h1, p11);
                p10 = fmaf(wb[0], h2, p10); p11 = fmaf(wb[1], h2, p11);
                p10 = fmaf(wb[2], h3, p10); p11 = fmaf(wb[3], h3, p11);
            }
        }
        // merge kh-halves (each pair's channels are split across l and l^32)
        p00 += __shfl_xor(p00, 32); p01 += __shfl_xor(p01, 32);
        p10 += __shfl_xor(p10, 32); p11 += __shfl_xor(p11, 32);

        const float o0 = (kh ? p10 : p00) + bf0;
        const float o1 = (kh ? p11 : p01) + bf1;
        const int i = i2 * 2 + kh;           // lane's kh picks its i-group
        const int j = jb * 32 + ln;
        *(f32x2*)(out + ((size_t)i * NCELL + j) * 2) = (f32x2){o0, o1};

        cpr0 = cpn0; cpr1 = cpn1;
    }
}

// ---------------------------------------------------------------- launcher
extern "C" void kernel_launch(void* const* d_in, const int* in_sizes, int n_in,
                              void* d_out, int out_size, void* d_ws, size_t ws_size,
                              hipStream_t stream) {
    const float* z   = (const float*)d_in[0];
    const float* W1  = (const float*)d_in[1];
    const float* b1  = (const float*)d_in[2];
    const float* W2  = (const float*)d_in[3];
    const float* b2  = (const float*)d_in[4];
    const float* Wf  = (const float*)d_in[5];
    const float* bfv = (const float*)d_in[6];
    float* out = (float*)d_out;

    float*  rp  = (float*)d_ws;                    // 768*256 f32
    float*  cp  = rp + NCELL * C1;                 // 768*256 f32
    __bf16* w2p = (__bf16*)(cp + NCELL * C1);      // 128*272 bf16

    prep_all<<<NCELL + (C2 * KP) / 256, 256, 0, stream>>>(z, W1, b1, W2, b2, rp, cp, w2p);
    pair_head<<<24 * WPG, 64, 0, stream>>>(rp, cp, w2p, Wf, bfv, out);
}

// Round 5
// 107.262 us; speedup vs baseline: 1.3146x; 1.3146x over previous
//
#include <hip/hip_runtime.h>

// SupNet pair-distance head, v4: 2-wave blocks, W2 split across the wave pair.
//   rp[j][c] = z[j]·W1[c,:128] + b1[c]   (c < 256)
//   cp[i][c] = z[i]·W1[c,128:]
//   h[m][c]  = relu(rp[j(m)][c] + cp[i(m)][c])            (bf16)
//   h2[n][m] = relu( W2[n][:]·h[m][:] + b2[n] )
//   out[m][o]= Wf[o][:]·h2[:][m] + bf[o]
//
// MFMA 32x32x16 bf16, A = W2-half (64 n-channels per wave), B = h (pairs).
// Wave nh holds w2f[2][16] = 128 VGPRs; epilogue combines the two waves'
// Wf-partials (linear) via LDS + 1 barrier/job. 2 waves/SIMD (8/CU).

typedef __attribute__((ext_vector_type(8)))  __bf16       bf16x8;
typedef __attribute__((ext_vector_type(2)))  float        f32x2;
typedef __attribute__((ext_vector_type(4)))  float        f32x4;
typedef __attribute__((ext_vector_type(16))) float        f32x16;
typedef __attribute__((ext_vector_type(4)))  unsigned int u32x4;

#define NCELL 768
#define DIM   128
#define C1    256
#define C2    128

// LDS map (bytes)
#define RP_STR 1040               // 1 KB row + 16B pad (4-bank row shift)
#define RP_OFF 0                  // 32 * 1040 = 33280
#define CP_OFF 33280              // 2 waves * 2048 (private cp slots)
#define WF_OFF 37376              // 128 * 8 = 1024
#define B2_OFF 38400              // 64 * 8 = 512
#define CB_OFF 38912              // 2 slots * 512 combine buffer
#define LDS_SZ 39936

// ---------------------------------------------------------------- helpers
static __device__ __forceinline__ f32x2 pk_add(f32x2 a, f32x2 b) {
    f32x2 d; asm("v_pk_add_f32 %0, %1, %2" : "=v"(d) : "v"(a), "v"(b)); return d;
}
static __device__ __forceinline__ f32x2 pk_fma(f32x2 a, f32x2 b, f32x2 c) {
    f32x2 d; asm("v_pk_fma_f32 %0, %1, %2, %3" : "=v"(d) : "v"(a), "v"(b), "v"(c)); return d;
}
static __device__ __forceinline__ f32x2 relu2(f32x2 a) {
    f32x2 d; d[0] = fmaxf(a[0], 0.f); d[1] = fmaxf(a[1], 0.f); return d;
}
static __device__ __forceinline__ unsigned cvtpk(float lo, float hi) {
    unsigned d; asm("v_cvt_pk_bf16_f32 %0, %1, %2" : "=v"(d) : "v"(lo), "v"(hi)); return d;
}
static __device__ __forceinline__ f32x2 lo2(f32x4 v) { return __builtin_shufflevector(v, v, 0, 1); }
static __device__ __forceinline__ f32x2 hi2(f32x4 v) { return __builtin_shufflevector(v, v, 2, 3); }

// ---------------------------------------------------------------- fused prep
// blocks 0..191: rp/cp for 4 j's each (W1 read once per 4 rows);
// blocks 192..319: W2 -> bf16.
__global__ __launch_bounds__(256) void prep_all(const float* __restrict__ z,
                                                const float* __restrict__ W1,
                                                const float* __restrict__ b1,
                                                const float* __restrict__ W2,
                                                float* __restrict__ rp,
                                                float* __restrict__ cp,
                                                __bf16* __restrict__ w2p) {
    const int tid = threadIdx.x;
    if (blockIdx.x < 192) {
        const int jb4 = blockIdx.x * 4;
        __shared__ float zl[4 * DIM];
        zl[tid]       = z[(size_t)jb4 * DIM + tid];
        zl[tid + 256] = z[(size_t)jb4 * DIM + tid + 256];
        __syncthreads();
        const int o = tid;
        float a1[4] = {0.f, 0.f, 0.f, 0.f};
        float a2[4] = {0.f, 0.f, 0.f, 0.f};
        const f32x4* w4 = (const f32x4*)(W1 + (size_t)o * (2 * DIM));
#pragma unroll 4
        for (int d4 = 0; d4 < 32; ++d4) {
            f32x4 wa = w4[d4], wb = w4[32 + d4];
#pragma unroll
            for (int jj = 0; jj < 4; ++jj) {
                f32x4 zv = *(const f32x4*)(zl + jj * DIM + d4 * 4);
#pragma unroll
                for (int e = 0; e < 4; ++e) {
                    a1[jj] = fmaf(zv[e], wa[e], a1[jj]);
                    a2[jj] = fmaf(zv[e], wb[e], a2[jj]);
                }
            }
        }
        const float bb = b1[o];
#pragma unroll
        for (int jj = 0; jj < 4; ++jj) {
            rp[(size_t)(jb4 + jj) * C1 + o] = a1[jj] + bb;
            cp[(size_t)(jb4 + jj) * C1 + o] = a2[jj];
        }
    } else {
        const int t = (blockIdx.x - 192) * 256 + tid;   // 0..32767
        w2p[t] = (__bf16)W2[t];
    }
}

// ---------------------------------------------------------------- main kernel
// grid = 24 jb-groups * 64 i-chunks = 1536 blocks * 128 thr; 6 jobs/block.
__global__ __launch_bounds__(128, 2) void pair_head(const float* __restrict__ rp,
                                                    const float* __restrict__ cp,
                                                    const __bf16* __restrict__ w2p,
                                                    const float* __restrict__ Wf,
                                                    const float* __restrict__ b2,
                                                    const float* __restrict__ bfv,
                                                    float* __restrict__ out) {
    __shared__ char smem[LDS_SZ];
    const int tid = threadIdx.x;
    const int nh  = tid >> 6;      // wave id = n-half
    const int l   = tid & 63;
    const int ln  = l & 31;
    const int kh  = l >> 5;
    const int jbg = blockIdx.x >> 6;     // 0..23
    const int ic  = blockIdx.x & 63;     // 0..63
    const int j0  = jbg * 32;

    // ---- stage rp j-tile (32 rows x 256 f32) — full tile, 128 threads
#pragma unroll
    for (int q = 0; q < 16; ++q) {
        int c = q * 128 + tid;
        int row = c >> 6, cc = c & 63;
        f32x4 v = *(const f32x4*)(rp + (size_t)(j0 + row) * C1 + cc * 4);
        *(f32x4*)(smem + RP_OFF + row * RP_STR + cc * 16) = v;
    }
    // ---- Wf permuted table: [kh][rp2][ngG][o] -> {Wf[o][n0], Wf[o][n0+1]}
    {
        int kk = tid >> 6, rp2 = (tid >> 3) & 7, ngG = (tid >> 1) & 3, o = tid & 1;
        int n0 = ngG * 32 + ((2 * rp2) & 3) + 8 * (rp2 >> 1) + 4 * kk;
        f32x2 e = {Wf[o * C2 + n0], Wf[o * C2 + n0 + 1]};
        *(f32x2*)(smem + WF_OFF + tid * 8) = e;
    }
    // ---- b2 permuted table: [kh][rp2][ngG]
    if (tid < 64) {
        int kk = tid >> 5, rp2 = (tid >> 2) & 7, ngG = tid & 3;
        int n0 = ngG * 32 + ((2 * rp2) & 3) + 8 * (rp2 >> 1) + 4 * kk;
        f32x2 e = {b2[n0], b2[n0 + 1]};
        *(f32x2*)(smem + B2_OFF + tid * 8) = e;
    }
    __syncthreads();

    // ---- W2 fragments for this wave's 64 n-channels: 128 VGPRs
    bf16x8 w2f[2][16];
#pragma unroll
    for (int ngL = 0; ngL < 2; ++ngL)
#pragma unroll
        for (int ks = 0; ks < 16; ++ks)
            w2f[ngL][ks] = *(const bf16x8*)(w2p + (size_t)((nh * 2 + ngL) * 32 + ln) * C1 + ks * 16 + kh * 8);

    const float bf0 = bfv[0], bf1 = bfv[1];

    for (int t = 0; t < 6; ++t) {
        const int i2 = ic * 6 + t;

        // ---- stage cp rows into this wave's private slots (no barrier needed)
        {
            const float* src = cp + (size_t)(i2 * 2 + kh) * C1 + ln * 8;
            f32x4 v0 = *(const f32x4*)(src);
            f32x4 v1 = *(const f32x4*)(src + 4);
            char* dst = smem + CP_OFF + nh * 2048 + kh * 1024 + ln * 32;
            *(f32x4*)(dst)      = v0;
            *(f32x4*)(dst + 16) = v1;
        }

        f32x16 acc[2][2];
#pragma unroll
        for (int g = 0; g < 2; ++g)
#pragma unroll
            for (int ngL = 0; ngL < 2; ++ngL)
                acc[g][ngL] = (f32x16)0.f;

        // ---- K loop: 16 steps of 16
#pragma unroll
        for (int ks = 0; ks < 16; ++ks) {
            const char* rb = smem + RP_OFF + ln * RP_STR + ks * 64 + kh * 32;
            f32x4 r0 = *(const f32x4*)(rb);
            f32x4 r1 = *(const f32x4*)(rb + 16);
            bf16x8 hb[2];
#pragma unroll
            for (int g = 0; g < 2; ++g) {
                const char* cb = smem + CP_OFF + nh * 2048 + g * 1024 + ks * 64 + kh * 32;
                f32x4 c0 = *(const f32x4*)(cb);
                f32x4 c1 = *(const f32x4*)(cb + 16);
                f32x2 s0 = relu2(pk_add(lo2(r0), lo2(c0)));
                f32x2 s1 = relu2(pk_add(hi2(r0), hi2(c0)));
                f32x2 s2 = relu2(pk_add(lo2(r1), lo2(c1)));
                f32x2 s3 = relu2(pk_add(hi2(r1), hi2(c1)));
                u32x4 hw;
                hw[0] = cvtpk(s0[0], s0[1]);
                hw[1] = cvtpk(s1[0], s1[1]);
                hw[2] = cvtpk(s2[0], s2[1]);
                hw[3] = cvtpk(s3[0], s3[1]);
                hb[g] = __builtin_bit_cast(bf16x8, hw);
            }
#pragma unroll
            for (int g = 0; g < 2; ++g)
#pragma unroll
                for (int ngL = 0; ngL < 2; ++ngL)
                    acc[g][ngL] = __builtin_amdgcn_mfma_f32_32x32x16_bf16(
                        w2f[ngL][ks], hb[g], acc[g][ngL], 0, 0, 0);
        }

        // ---- epilogue: h2 = relu(acc + b2); partial Wf-dot over this n-half
        f32x2 P[2][2];
        P[0][0] = (f32x2){0.f, 0.f}; P[0][1] = (f32x2){0.f, 0.f};
        P[1][0] = (f32x2){0.f, 0.f}; P[1][1] = (f32x2){0.f, 0.f};
#pragma unroll
        for (int rp2 = 0; rp2 < 8; ++rp2) {
#pragma unroll
            for (int ngL = 0; ngL < 2; ++ngL) {
                const int ngG = nh * 2 + ngL;
                const char* wbase = smem + WF_OFF + ((size_t)(kh * 8 + rp2) * 4 + ngG) * 16;
                f32x2 w0 = *(const f32x2*)(wbase);
                f32x2 w1 = *(const f32x2*)(wbase + 8);
                f32x2 bb = *(const f32x2*)(smem + B2_OFF + ((size_t)(kh * 8 + rp2) * 4 + ngG) * 8);
#pragma unroll
                for (int g = 0; g < 2; ++g) {
                    f32x2 s = {acc[g][ngL][2 * rp2], acc[g][ngL][2 * rp2 + 1]};
                    s = relu2(pk_add(s, bb));
                    P[g][0] = pk_fma(w0, s, P[g][0]);
                    P[g][1] = pk_fma(w1, s, P[g][1]);
                }
            }
        }
        float p00 = P[0][0][0] + P[0][0][1];
        float p01 = P[0][1][0] + P[0][1][1];
        float p10 = P[1][0][0] + P[1][0][1];
        float p11 = P[1][1][0] + P[1][1][1];
        // merge kh halves (n-rows split across lane pairs l, l^32)
        p00 += __shfl_xor(p00, 32); p01 += __shfl_xor(p01, 32);
        p10 += __shfl_xor(p10, 32); p11 += __shfl_xor(p11, 32);

        const int slot = t & 1;
        if (nh == 1) {   // publish partials; half kh covers pair-group g=kh
            f32x2 e = {kh ? p10 : p00, kh ? p11 : p01};
            *(f32x2*)(smem + CB_OFF + slot * 512 + kh * 256 + ln * 8) = e;
        }
        __syncthreads();
        if (nh == 0) {   // combine + store
            f32x2 q = *(const f32x2*)(smem + CB_OFF + slot * 512 + kh * 256 + ln * 8);
            float o0 = (kh ? p10 : p00) + q[0] + bf0;
            float o1 = (kh ? p11 : p01) + q[1] + bf1;
            const int i = i2 * 2 + kh;
            const int j = j0 + ln;
            *(f32x2*)(out + ((size_t)i * NCELL + j) * 2) = (f32x2){o0, o1};
        }
    }
}

// ---------------------------------------------------------------- launcher
extern "C" void kernel_launch(void* const* d_in, const int* in_sizes, int n_in,
                              void* d_out, int out_size, void* d_ws, size_t ws_size,
                              hipStream_t stream) {
    const float* z   = (const float*)d_in[0];
    const float* W1  = (const float*)d_in[1];
    const float* b1  = (const float*)d_in[2];
    const float* W2  = (const float*)d_in[3];
    const float* b2  = (const float*)d_in[4];
    const float* Wf  = (const float*)d_in[5];
    const float* bfv = (const float*)d_in[6];
    float* out = (float*)d_out;

    float*  rp  = (float*)d_ws;                    // 768*256 f32
    float*  cp  = rp + NCELL * C1;                 // 768*256 f32
    __bf16* w2p = (__bf16*)(cp + NCELL * C1);      // 128*256 bf16

    prep_all<<<192 + 128, 256, 0, stream>>>(z, W1, b1, W2, rp, cp, w2p);
    pair_head<<<24 * 64, 128, 0, stream>>>(rp, cp, w2p, Wf, b2, bfv, out);
}

// Round 7
// 103.791 us; speedup vs baseline: 1.3586x; 1.0334x over previous
//
#include <hip/hip_runtime.h>

// SupNet pair-distance head, v5b: 4-wave blocks, 4-way n-split, f16 h/W2.
//   rp[j][c] = z[j]·W1[c,:128] + b1[c]
//   cp[i][c] = z[i]·W1[c,128:]
//   h[m][c]  = relu(rp[j][c] + cp[i][c])          (f16)
//   h2[n][m] = relu( W2[n][:]·h[m][:] + b2[n] )
//   out[m][o]= Wf[o][:]·h2[:][m] + bf[o]
//
// MFMA 32x32x16 f16. Wave nh owns 32 n-channels (w2f[16] = 64 VGPRs).
// Job = 1 i x 32 j; acc = 1 f32x16. Target <=128 regs -> 4 waves/SIMD,
// LDS 38.9KB -> 4 blocks/CU (16 waves/CU). 1 barrier/job, rotating combiner.

typedef __attribute__((ext_vector_type(8)))  _Float16     f16x8;
typedef __attribute__((ext_vector_type(2)))  __fp16       hf16x2;
typedef __attribute__((ext_vector_type(2)))  float        f32x2;
typedef __attribute__((ext_vector_type(4)))  float        f32x4;
typedef __attribute__((ext_vector_type(16))) float        f32x16;
typedef __attribute__((ext_vector_type(4)))  unsigned int u32x4;

#define NCELL 768
#define DIM   128
#define C1    256
#define C2    128

// LDS map (bytes)
#define RP_OFF 0          // 32 rows * 1040 = 33280
#define RP_STR 1040
#define CPB    33280      // 2 * 1024 cp double-buffer
#define CB     35328      // 2 * 1024 combine slots (4 waves * 32 * 8B)
#define WFT    37376      // 64 * 16
#define B2T    38400      // 64 * 8
#define LDS_SZ 38912

// ---------------------------------------------------------------- helpers
static __device__ __forceinline__ f32x2 pk_add(f32x2 a, f32x2 b) {
    f32x2 d; asm("v_pk_add_f32 %0, %1, %2" : "=v"(d) : "v"(a), "v"(b)); return d;
}
static __device__ __forceinline__ f32x2 pk_fma(f32x2 a, f32x2 b, f32x2 c) {
    f32x2 d; asm("v_pk_fma_f32 %0, %1, %2, %3" : "=v"(d) : "v"(a), "v"(b), "v"(c)); return d;
}
static __device__ __forceinline__ f32x2 relu2(f32x2 a) {
    f32x2 d; d[0] = fmaxf(a[0], 0.f); d[1] = fmaxf(a[1], 0.f); return d;
}
static __device__ __forceinline__ unsigned cvt2h(float a, float b) {
    hf16x2 h = __builtin_amdgcn_cvt_pkrtz(a, b);
    return __builtin_bit_cast(unsigned, h);
}
static __device__ __forceinline__ f32x2 lo2(f32x4 v) { return __builtin_shufflevector(v, v, 0, 1); }
static __device__ __forceinline__ f32x2 hi2(f32x4 v) { return __builtin_shufflevector(v, v, 2, 3); }

// ---------------------------------------------------------------- fused prep
// blocks 0..191: rp/cp for 4 j's each; blocks 192..319: W2 -> f16.
__global__ __launch_bounds__(256) void prep_all(const float* __restrict__ z,
                                                const float* __restrict__ W1,
                                                const float* __restrict__ b1,
                                                const float* __restrict__ W2,
                                                float* __restrict__ rp,
                                                float* __restrict__ cp,
                                                _Float16* __restrict__ w2h) {
    const int tid = threadIdx.x;
    if (blockIdx.x < 192) {
        const int jb4 = blockIdx.x * 4;
        __shared__ float zl[4 * DIM];
        zl[tid]       = z[(size_t)jb4 * DIM + tid];
        zl[tid + 256] = z[(size_t)jb4 * DIM + tid + 256];
        __syncthreads();
        const int o = tid;
        float a1[4] = {0.f, 0.f, 0.f, 0.f};
        float a2[4] = {0.f, 0.f, 0.f, 0.f};
        const f32x4* w4 = (const f32x4*)(W1 + (size_t)o * (2 * DIM));
#pragma unroll 4
        for (int d4 = 0; d4 < 32; ++d4) {
            f32x4 wa = w4[d4], wb = w4[32 + d4];
#pragma unroll
            for (int jj = 0; jj < 4; ++jj) {
                f32x4 zv = *(const f32x4*)(zl + jj * DIM + d4 * 4);
#pragma unroll
                for (int e = 0; e < 4; ++e) {
                    a1[jj] = fmaf(zv[e], wa[e], a1[jj]);
                    a2[jj] = fmaf(zv[e], wb[e], a2[jj]);
                }
            }
        }
        const float bb = b1[o];
#pragma unroll
        for (int jj = 0; jj < 4; ++jj) {
            rp[(size_t)(jb4 + jj) * C1 + o] = a1[jj] + bb;
            cp[(size_t)(jb4 + jj) * C1 + o] = a2[jj];
        }
    } else {
        const int t = (blockIdx.x - 192) * 256 + tid;   // 0..32767
        w2h[t] = (_Float16)W2[t];
    }
}

// ---------------------------------------------------------------- main kernel
// grid = 24 jb-groups * 64 i-chunks = 1536 blocks * 256 thr; 12 jobs/block.
__global__ __launch_bounds__(256, 4) void pair_head(const float* __restrict__ rp,
                                                    const float* __restrict__ cp,
                                                    const _Float16* __restrict__ w2h,
                                                    const float* __restrict__ Wf,
                                                    const float* __restrict__ b2,
                                                    const float* __restrict__ bfv,
                                                    float* __restrict__ out) {
    __shared__ char smem[LDS_SZ];
    const int tid = threadIdx.x;
    const int nh  = tid >> 6;      // wave id = n-quarter
    const int l   = tid & 63;
    const int ln  = l & 31;
    const int kh  = l >> 5;
    const int jbg = blockIdx.x >> 6;     // 0..23
    const int ic  = blockIdx.x & 63;     // 0..63
    const int j0  = jbg * 32;
    const int i_base = ic * 12;

    // ---- stage rp j-tile: 8192 f32 over 256 threads
#pragma unroll
    for (int q = 0; q < 8; ++q) {
        int c = q * 256 + tid;
        int row = c >> 6, cc = c & 63;
        f32x4 v = *(const f32x4*)(rp + (size_t)(j0 + row) * C1 + cc * 4);
        *(f32x4*)(smem + RP_OFF + row * RP_STR + cc * 16) = v;
    }
    // ---- Wf table: idx = kk*32 + q*4 + ng -> {Wf0[n0],Wf0[n0+1],Wf1[n0],Wf1[n0+1]}
    if (tid < 128) {
        int idx = tid >> 1, o = tid & 1;
        int kk = idx >> 5, q = (idx >> 2) & 7, ng = idx & 3;
        int r = 2 * q;
        int n0 = ng * 32 + (r & 3) + 8 * (r >> 2) + 4 * kk;
        f32x2 e = {Wf[o * C2 + n0], Wf[o * C2 + n0 + 1]};
        *(f32x2*)(smem + WFT + idx * 16 + o * 8) = e;
    }
    // ---- b2 table
    if (tid < 64) {
        int idx = tid;
        int kk = idx >> 5, q = (idx >> 2) & 7, ng = idx & 3;
        int r = 2 * q;
        int n0 = ng * 32 + (r & 3) + 8 * (r >> 2) + 4 * kk;
        f32x2 e = {b2[n0], b2[n0 + 1]};
        *(f32x2*)(smem + B2T + idx * 8) = e;
    }
    // ---- cp for job 0 into slot 0
    {
        float v = cp[(size_t)i_base * C1 + tid];
        *(float*)(smem + CPB + tid * 4) = v;
    }
    // ---- W2 quarter in registers: 64 VGPRs
    f16x8 w2f[16];
#pragma unroll
    for (int ks = 0; ks < 16; ++ks)
        w2f[ks] = *(const f16x8*)(w2h + (size_t)(nh * 32 + ln) * C1 + ks * 16 + kh * 8);

    __syncthreads();

    const float bf0 = bfv[0], bf1 = bfv[1];
    const char* rbbase = smem + RP_OFF + ln * RP_STR + kh * 32;

    for (int t = 0; t < 12; ++t) {
        // ---- prefetch next job's cp row (issue early, write late)
        float cpv = 0.f;
        if (t < 11) cpv = cp[(size_t)(i_base + t + 1) * C1 + tid];

        const char* cbbase = smem + CPB + (t & 1) * 1024 + kh * 32;

        f32x16 acc = (f32x16)0.f;
#pragma unroll
        for (int ks = 0; ks < 16; ++ks) {
            f32x4 r0 = *(const f32x4*)(rbbase + ks * 64);
            f32x4 r1 = *(const f32x4*)(rbbase + ks * 64 + 16);
            f32x4 c0 = *(const f32x4*)(cbbase + ks * 64);
            f32x4 c1 = *(const f32x4*)(cbbase + ks * 64 + 16);
            f32x2 s0 = pk_add(lo2(r0), lo2(c0));
            f32x2 s1 = pk_add(hi2(r0), hi2(c0));
            f32x2 s2 = pk_add(lo2(r1), lo2(c1));
            f32x2 s3 = pk_add(hi2(r1), hi2(c1));
            u32x4 hw;
            hw[0] = cvt2h(fmaxf(s0[0], 0.f), fmaxf(s0[1], 0.f));
            hw[1] = cvt2h(fmaxf(s1[0], 0.f), fmaxf(s1[1], 0.f));
            hw[2] = cvt2h(fmaxf(s2[0], 0.f), fmaxf(s2[1], 0.f));
            hw[3] = cvt2h(fmaxf(s3[0], 0.f), fmaxf(s3[1], 0.f));
            f16x8 hb = __builtin_bit_cast(f16x8, hw);
            acc = __builtin_amdgcn_mfma_f32_32x32x16_f16(w2f[ks], hb, acc, 0, 0, 0);
        }

        // ---- epilogue: h2 = relu(acc + b2); partial Wf-dot over 32 channels
        f32x2 P0 = {0.f, 0.f}, P1 = {0.f, 0.f};
#pragma unroll
        for (int q = 0; q < 8; ++q) {
            int idx = kh * 32 + q * 4 + nh;
            f32x4 w01 = *(const f32x4*)(smem + WFT + idx * 16);
            f32x2 bb  = *(const f32x2*)(smem + B2T + idx * 8);
            f32x2 s = {acc[2 * q], acc[2 * q + 1]};
            s = relu2(pk_add(s, bb));
            P0 = pk_fma(lo2(w01), s, P0);
            P1 = pk_fma(hi2(w01), s, P1);
        }
        float p0 = P0[0] + P0[1], p1 = P1[0] + P1[1];
        p0 += __shfl_xor(p0, 32);
        p1 += __shfl_xor(p1, 32);
        if (kh == 0)
            *(f32x2*)(smem + CB + (t & 1) * 1024 + nh * 256 + ln * 8) = (f32x2){p0, p1};

        // ---- write prefetched cp (latency hidden under K-loop + epilogue)
        if (t < 11)
            *(float*)(smem + CPB + ((t + 1) & 1) * 1024 + tid * 4) = cpv;

        __syncthreads();

        // ---- rotating combiner: wave (t&3), lanes kh==0
        if (nh == (t & 3) && kh == 0) {
            const char* cbse = smem + CB + (t & 1) * 1024 + ln * 8;
            f32x2 a0 = *(const f32x2*)(cbse);
            f32x2 a1 = *(const f32x2*)(cbse + 256);
            f32x2 a2 = *(const f32x2*)(cbse + 512);
            f32x2 a3 = *(const f32x2*)(cbse + 768);
            float o0 = a0[0] + a1[0] + a2[0] + a3[0] + bf0;
            float o1 = a0[1] + a1[1] + a2[1] + a3[1] + bf1;
            const int i = i_base + t;
            *(f32x2*)(out + ((size_t)i * NCELL + j0 + ln) * 2) = (f32x2){o0, o1};
        }
    }
}

// ---------------------------------------------------------------- launcher
extern "C" void kernel_launch(void* const* d_in, const int* in_sizes, int n_in,
                              void* d_out, int out_size, void* d_ws, size_t ws_size,
                              hipStream_t stream) {
    const float* z   = (const float*)d_in[0];
    const float* W1  = (const float*)d_in[1];
    const float* b1  = (const float*)d_in[2];
    const float* W2  = (const float*)d_in[3];
    const float* b2  = (const float*)d_in[4];
    const float* Wf  = (const float*)d_in[5];
    const float* bfv = (const float*)d_in[6];
    float* out = (float*)d_out;

    float*    rp  = (float*)d_ws;                  // 768*256 f32
    float*    cp  = rp + NCELL * C1;               // 768*256 f32
    _Float16* w2h = (_Float16*)(cp + NCELL * C1);  // 128*256 f16

    prep_all<<<192 + 128, 256, 0, stream>>>(z, W1, b1, W2, rp, cp, w2h);
    pair_head<<<24 * 64, 256, 0, stream>>>(rp, cp, w2h, Wf, b2, bfv, out);
}

// Round 8
// 77.128 us; speedup vs baseline: 1.8283x; 1.3457x over previous
//
#include <hip/hip_runtime.h>

// SupNet pair-distance head, v6: rp B-fragments held in REGISTERS (f16),
// zero rp LDS traffic in the K-loop; cp via tiny broadcast LDS reads.
//   rp16[j][c] = f16( z[j]·W1[c,:128] + b1[c] )
//   cp16[i][c] = f16( z[i]·W1[c,128:] )
//   h[m][c]  = relu(rp16 + cp16)            (f16 math)
//   h2[n][m] = relu( W2[n][:]·h[m][:] + b2[n] )
//   out[m][o]= Wf[o][:]·h2[:][m] + bf[o]
//
// MFMA 32x32x16 f16. 4 waves/block, wave nh owns 32 n-channels.
// Regs/wave: rpf[16] (64) + w2f[16] (64) + acc (16) + temps -> ~175.
// LDS only 4.6 KB (cp dbuf + combine + tables). 1 barrier/job.

typedef __attribute__((ext_vector_type(8)))  _Float16     f16x8;
typedef __attribute__((ext_vector_type(2)))  float        f32x2;
typedef __attribute__((ext_vector_type(4)))  float        f32x4;
typedef __attribute__((ext_vector_type(16))) float        f32x16;

#define NCELL 768
#define DIM   128
#define C1    256
#define C2    128

// LDS map (bytes)
#define CPB    0          // 2 * 512  cp16 double-buffer
#define CB     1024       // 2 * 1024 combine slots (4 waves * 32 * 8B)
#define WFT    3072       // 64 * 16
#define B2T    4096       // 64 * 8
#define LDS_SZ 4608

// ---------------------------------------------------------------- helpers
static __device__ __forceinline__ f32x2 pk_add(f32x2 a, f32x2 b) {
    f32x2 d; asm("v_pk_add_f32 %0, %1, %2" : "=v"(d) : "v"(a), "v"(b)); return d;
}
static __device__ __forceinline__ f32x2 pk_fma(f32x2 a, f32x2 b, f32x2 c) {
    f32x2 d; asm("v_pk_fma_f32 %0, %1, %2, %3" : "=v"(d) : "v"(a), "v"(b), "v"(c)); return d;
}
static __device__ __forceinline__ f32x2 relu2(f32x2 a) {
    f32x2 d; d[0] = fmaxf(a[0], 0.f); d[1] = fmaxf(a[1], 0.f); return d;
}
static __device__ __forceinline__ f32x2 lo2(f32x4 v) { return __builtin_shufflevector(v, v, 0, 1); }
static __device__ __forceinline__ f32x2 hi2(f32x4 v) { return __builtin_shufflevector(v, v, 2, 3); }

// ---------------------------------------------------------------- fused prep
// blocks 0..191: rp16/cp16 for 4 j's each; blocks 192..319: W2 -> f16.
__global__ __launch_bounds__(256) void prep_all(const float* __restrict__ z,
                                                const float* __restrict__ W1,
                                                const float* __restrict__ b1,
                                                const float* __restrict__ W2,
                                                _Float16* __restrict__ rp16,
                                                _Float16* __restrict__ cp16,
                                                _Float16* __restrict__ w2h) {
    const int tid = threadIdx.x;
    if (blockIdx.x < 192) {
        const int jb4 = blockIdx.x * 4;
        __shared__ float zl[4 * DIM];
        zl[tid]       = z[(size_t)jb4 * DIM + tid];
        zl[tid + 256] = z[(size_t)jb4 * DIM + tid + 256];
        __syncthreads();
        const int o = tid;
        float a1[4] = {0.f, 0.f, 0.f, 0.f};
        float a2[4] = {0.f, 0.f, 0.f, 0.f};
        const f32x4* w4 = (const f32x4*)(W1 + (size_t)o * (2 * DIM));
#pragma unroll 4
        for (int d4 = 0; d4 < 32; ++d4) {
            f32x4 wa = w4[d4], wb = w4[32 + d4];
#pragma unroll
            for (int jj = 0; jj < 4; ++jj) {
                f32x4 zv = *(const f32x4*)(zl + jj * DIM + d4 * 4);
#pragma unroll
                for (int e = 0; e < 4; ++e) {
                    a1[jj] = fmaf(zv[e], wa[e], a1[jj]);
                    a2[jj] = fmaf(zv[e], wb[e], a2[jj]);
                }
            }
        }
        const float bb = b1[o];
#pragma unroll
        for (int jj = 0; jj < 4; ++jj) {
            rp16[(size_t)(jb4 + jj) * C1 + o] = (_Float16)(a1[jj] + bb);
            cp16[(size_t)(jb4 + jj) * C1 + o] = (_Float16)a2[jj];
        }
    } else {
        const int t = (blockIdx.x - 192) * 256 + tid;   // 0..32767
        w2h[t] = (_Float16)W2[t];
    }
}

// ---------------------------------------------------------------- main kernel
// grid = 24 jb-groups * 64 i-chunks = 1536 blocks * 256 thr; 12 jobs/block.
__global__ __launch_bounds__(256, 2) void pair_head(const _Float16* __restrict__ rp16,
                                                    const _Float16* __restrict__ cp16,
                                                    const _Float16* __restrict__ w2h,
                                                    const float* __restrict__ Wf,
                                                    const float* __restrict__ b2,
                                                    const float* __restrict__ bfv,
                                                    float* __restrict__ out) {
    __shared__ char smem[LDS_SZ];
    const int tid = threadIdx.x;
    const int nh  = tid >> 6;      // wave id = n-quarter
    const int l   = tid & 63;
    const int ln  = l & 31;
    const int kh  = l >> 5;
    const int jbg = blockIdx.x >> 6;     // 0..23
    const int ic  = blockIdx.x & 63;     // 0..63
    const int j0  = jbg * 32;
    const int i_base = ic * 12;

    // ---- Wf table: idx = kk*32 + q*4 + ng -> {Wf0[n0],Wf0[n0+1],Wf1[n0],Wf1[n0+1]}
    if (tid < 128) {
        int idx = tid >> 1, o = tid & 1;
        int kk = idx >> 5, q = (idx >> 2) & 7, ng = idx & 3;
        int r = 2 * q;
        int n0 = ng * 32 + (r & 3) + 8 * (r >> 2) + 4 * kk;
        f32x2 e = {Wf[o * C2 + n0], Wf[o * C2 + n0 + 1]};
        *(f32x2*)(smem + WFT + idx * 16 + o * 8) = e;
    }
    // ---- b2 table
    if (tid < 64) {
        int idx = tid;
        int kk = idx >> 5, q = (idx >> 2) & 7, ng = idx & 3;
        int r = 2 * q;
        int n0 = ng * 32 + (r & 3) + 8 * (r >> 2) + 4 * kk;
        f32x2 e = {b2[n0], b2[n0 + 1]};
        *(f32x2*)(smem + B2T + idx * 8) = e;
    }
    // ---- cp16 for job 0 into slot 0 (512 B)
    if (tid < 128) {
        unsigned v = *(const unsigned*)((const char*)cp16 + (size_t)i_base * 512 + tid * 4);
        *(unsigned*)(smem + CPB + tid * 4) = v;
    }

    // ---- rp B-fragments in registers: 64 VGPRs (constant over all 12 jobs)
    f16x8 rpf[16];
    {
        const char* rsrc = (const char*)rp16 + (size_t)(j0 + ln) * 512 + kh * 16;
#pragma unroll
        for (int ks = 0; ks < 16; ++ks)
            rpf[ks] = *(const f16x8*)(rsrc + ks * 32);
    }
    // ---- W2 quarter in registers: 64 VGPRs
    f16x8 w2f[16];
#pragma unroll
    for (int ks = 0; ks < 16; ++ks)
        w2f[ks] = *(const f16x8*)(w2h + (size_t)(nh * 32 + ln) * C1 + ks * 16 + kh * 8);

    __syncthreads();

    const float bf0 = bfv[0], bf1 = bfv[1];
    const f16x8 zero8 = (f16x8)(_Float16)0.0f;

    for (int t = 0; t < 12; ++t) {
        // ---- prefetch next job's cp16 row (issue early, write late)
        unsigned cpv = 0;
        if (t < 11 && tid < 128)
            cpv = *(const unsigned*)((const char*)cp16 + (size_t)(i_base + t + 1) * 512 + tid * 4);

        const char* cbbase = smem + CPB + (t & 1) * 512 + kh * 16;

        f32x16 acc = (f32x16)0.f;
#pragma unroll
        for (int ks = 0; ks < 16; ++ks) {
            f16x8 cv = *(const f16x8*)(cbbase + ks * 32);   // broadcast read
            f16x8 hb = __builtin_elementwise_max(rpf[ks] + cv, zero8);
            acc = __builtin_amdgcn_mfma_f32_32x32x16_f16(w2f[ks], hb, acc, 0, 0, 0);
        }

        // ---- epilogue: h2 = relu(acc + b2); partial Wf-dot over 32 channels
        f32x2 P0 = {0.f, 0.f}, P1 = {0.f, 0.f};
#pragma unroll
        for (int q = 0; q < 8; ++q) {
            int idx = kh * 32 + q * 4 + nh;
            f32x4 w01 = *(const f32x4*)(smem + WFT + idx * 16);
            f32x2 bb  = *(const f32x2*)(smem + B2T + idx * 8);
            f32x2 s = {acc[2 * q], acc[2 * q + 1]};
            s = relu2(pk_add(s, bb));
            P0 = pk_fma(lo2(w01), s, P0);
            P1 = pk_fma(hi2(w01), s, P1);
        }
        float p0 = P0[0] + P0[1], p1 = P1[0] + P1[1];
        p0 += __shfl_xor(p0, 32);
        p1 += __shfl_xor(p1, 32);
        if (kh == 0)
            *(f32x2*)(smem + CB + (t & 1) * 1024 + nh * 256 + ln * 8) = (f32x2){p0, p1};

        // ---- write prefetched cp16 (latency hidden under K-loop + epilogue)
        if (t < 11 && tid < 128)
            *(unsigned*)(smem + CPB + ((t + 1) & 1) * 512 + tid * 4) = cpv;

        __syncthreads();

        // ---- rotating combiner: wave (t&3), lanes kh==0
        if (nh == (t & 3) && kh == 0) {
            const char* cbse = smem + CB + (t & 1) * 1024 + ln * 8;
            f32x2 a0 = *(const f32x2*)(cbse);
            f32x2 a1 = *(const f32x2*)(cbse + 256);
            f32x2 a2 = *(const f32x2*)(cbse + 512);
            f32x2 a3 = *(const f32x2*)(cbse + 768);
            float o0 = a0[0] + a1[0] + a2[0] + a3[0] + bf0;
            float o1 = a0[1] + a1[1] + a2[1] + a3[1] + bf1;
            const int i = i_base + t;
            *(f32x2*)(out + ((size_t)i * NCELL + j0 + ln) * 2) = (f32x2){o0, o1};
        }
    }
}

// ---------------------------------------------------------------- launcher
extern "C" void kernel_launch(void* const* d_in, const int* in_sizes, int n_in,
                              void* d_out, int out_size, void* d_ws, size_t ws_size,
                              hipStream_t stream) {
    const float* z   = (const float*)d_in[0];
    const float* W1  = (const float*)d_in[1];
    const float* b1  = (const float*)d_in[2];
    const float* W2  = (const float*)d_in[3];
    const float* b2  = (const float*)d_in[4];
    const float* Wf  = (const float*)d_in[5];
    const float* bfv = (const float*)d_in[6];
    float* out = (float*)d_out;

    _Float16* rp16 = (_Float16*)d_ws;                 // 768*256 f16
    _Float16* cp16 = rp16 + NCELL * C1;               // 768*256 f16
    _Float16* w2h  = cp16 + NCELL * C1;               // 128*256 f16

    prep_all<<<192 + 128, 256, 0, stream>>>(z, W1, b1, W2, rp16, cp16, w2h);
    pair_head<<<24 * 64, 256, 0, stream>>>(rp16, cp16, w2h, Wf, b2, bfv, out);
}

// Round 9
// 74.136 us; speedup vs baseline: 1.9021x; 1.0404x over previous
//
#include <hip/hip_runtime.h>

// SupNet pair-distance head, v7: v6 + 2 i's per job (2 independent MFMA
// chains, half the barriers).
//   rp16[j][c] = f16( z[j]·W1[c,:128] + b1[c] )
//   cp16[i][c] = f16( z[i]·W1[c,128:] )
//   h[m][c]  = relu(rp16 + cp16)            (f16 math)
//   h2[n][m] = relu( W2[n][:]·h[m][:] + b2[n] )
//   out[m][o]= Wf[o][:]·h2[:][m] + bf[o]
//
// MFMA 32x32x16 f16. 4 waves/block, wave nh owns 32 n-channels.
// rpf[16] + w2f[16] in registers; cp via broadcast LDS; job = 2 i x 32 j.

typedef __attribute__((ext_vector_type(8)))  _Float16     f16x8;
typedef __attribute__((ext_vector_type(2)))  float        f32x2;
typedef __attribute__((ext_vector_type(4)))  float        f32x4;
typedef __attribute__((ext_vector_type(16))) float        f32x16;

#define NCELL 768
#define DIM   128
#define C1    256
#define C2    128

// LDS map (bytes)
#define CPB    0          // 2 slots * 1024 (cp16 for 2 i-rows)
#define CB     2048       // 2 slots * 2048 (4 waves * 2 ii * 32 * 8B)
#define WFT    6144       // 64 * 16
#define B2T    7168       // 64 * 8
#define LDS_SZ 7680

// ---------------------------------------------------------------- helpers
static __device__ __forceinline__ f32x2 pk_add(f32x2 a, f32x2 b) {
    f32x2 d; asm("v_pk_add_f32 %0, %1, %2" : "=v"(d) : "v"(a), "v"(b)); return d;
}
static __device__ __forceinline__ f32x2 pk_fma(f32x2 a, f32x2 b, f32x2 c) {
    f32x2 d; asm("v_pk_fma_f32 %0, %1, %2, %3" : "=v"(d) : "v"(a), "v"(b), "v"(c)); return d;
}
static __device__ __forceinline__ f32x2 relu2(f32x2 a) {
    f32x2 d; d[0] = fmaxf(a[0], 0.f); d[1] = fmaxf(a[1], 0.f); return d;
}
static __device__ __forceinline__ f32x2 lo2(f32x4 v) { return __builtin_shufflevector(v, v, 0, 1); }
static __device__ __forceinline__ f32x2 hi2(f32x4 v) { return __builtin_shufflevector(v, v, 2, 3); }

// ---------------------------------------------------------------- fused prep
// blocks 0..191: rp16/cp16 for 4 j's each; blocks 192..319: W2 -> f16.
__global__ __launch_bounds__(256) void prep_all(const float* __restrict__ z,
                                                const float* __restrict__ W1,
                                                const float* __restrict__ b1,
                                                const float* __restrict__ W2,
                                                _Float16* __restrict__ rp16,
                                                _Float16* __restrict__ cp16,
                                                _Float16* __restrict__ w2h) {
    const int tid = threadIdx.x;
    if (blockIdx.x < 192) {
        const int jb4 = blockIdx.x * 4;
        __shared__ float zl[4 * DIM];
        zl[tid]       = z[(size_t)jb4 * DIM + tid];
        zl[tid + 256] = z[(size_t)jb4 * DIM + tid + 256];
        __syncthreads();
        const int o = tid;
        float a1[4] = {0.f, 0.f, 0.f, 0.f};
        float a2[4] = {0.f, 0.f, 0.f, 0.f};
        const f32x4* w4 = (const f32x4*)(W1 + (size_t)o * (2 * DIM));
#pragma unroll 4
        for (int d4 = 0; d4 < 32; ++d4) {
            f32x4 wa = w4[d4], wb = w4[32 + d4];
#pragma unroll
            for (int jj = 0; jj < 4; ++jj) {
                f32x4 zv = *(const f32x4*)(zl + jj * DIM + d4 * 4);
#pragma unroll
                for (int e = 0; e < 4; ++e) {
                    a1[jj] = fmaf(zv[e], wa[e], a1[jj]);
                    a2[jj] = fmaf(zv[e], wb[e], a2[jj]);
                }
            }
        }
        const float bb = b1[o];
#pragma unroll
        for (int jj = 0; jj < 4; ++jj) {
            rp16[(size_t)(jb4 + jj) * C1 + o] = (_Float16)(a1[jj] + bb);
            cp16[(size_t)(jb4 + jj) * C1 + o] = (_Float16)a2[jj];
        }
    } else {
        const int t = (blockIdx.x - 192) * 256 + tid;   // 0..32767
        w2h[t] = (_Float16)W2[t];
    }
}

// ---------------------------------------------------------------- main kernel
// grid = 24 jb-groups * 64 i-chunks = 1536 blocks * 256 thr; 6 jobs * 2 i.
__global__ __launch_bounds__(256, 2) void pair_head(const _Float16* __restrict__ rp16,
                                                    const _Float16* __restrict__ cp16,
                                                    const _Float16* __restrict__ w2h,
                                                    const float* __restrict__ Wf,
                                                    const float* __restrict__ b2,
                                                    const float* __restrict__ bfv,
                                                    float* __restrict__ out) {
    __shared__ char smem[LDS_SZ];
    const int tid = threadIdx.x;
    const int nh  = tid >> 6;      // wave id = n-quarter
    const int l   = tid & 63;
    const int ln  = l & 31;
    const int kh  = l >> 5;
    const int jbg = blockIdx.x >> 6;     // 0..23
    const int ic  = blockIdx.x & 63;     // 0..63
    const int j0  = jbg * 32;
    const int i_base = ic * 12;

    // ---- Wf table: idx = kk*32 + q*4 + ng -> {Wf0[n0],Wf0[n0+1],Wf1[n0],Wf1[n0+1]}
    if (tid < 128) {
        int idx = tid >> 1, o = tid & 1;
        int kk = idx >> 5, q = (idx >> 2) & 7, ng = idx & 3;
        int r = 2 * q;
        int n0 = ng * 32 + (r & 3) + 8 * (r >> 2) + 4 * kk;
        f32x2 e = {Wf[o * C2 + n0], Wf[o * C2 + n0 + 1]};
        *(f32x2*)(smem + WFT + idx * 16 + o * 8) = e;
    }
    // ---- b2 table
    if (tid < 64) {
        int idx = tid;
        int kk = idx >> 5, q = (idx >> 2) & 7, ng = idx & 3;
        int r = 2 * q;
        int n0 = ng * 32 + (r & 3) + 8 * (r >> 2) + 4 * kk;
        f32x2 e = {b2[n0], b2[n0 + 1]};
        *(f32x2*)(smem + B2T + idx * 8) = e;
    }
    // ---- cp16 for job 0 (2 rows = 1 KB) into slot 0
    {
        unsigned v = *(const unsigned*)((const char*)cp16 + (size_t)i_base * 512 + tid * 4);
        *(unsigned*)(smem + CPB + tid * 4) = v;
    }

    // ---- rp B-fragments in registers: 64 VGPRs (constant over all jobs)
    f16x8 rpf[16];
    {
        const char* rsrc = (const char*)rp16 + (size_t)(j0 + ln) * 512 + kh * 16;
#pragma unroll
        for (int ks = 0; ks < 16; ++ks)
            rpf[ks] = *(const f16x8*)(rsrc + ks * 32);
    }
    // ---- W2 quarter in registers: 64 VGPRs
    f16x8 w2f[16];
#pragma unroll
    for (int ks = 0; ks < 16; ++ks)
        w2f[ks] = *(const f16x8*)(w2h + (size_t)(nh * 32 + ln) * C1 + ks * 16 + kh * 8);

    __syncthreads();

    const float bf0 = bfv[0], bf1 = bfv[1];
    const f16x8 zero8 = (f16x8)(_Float16)0.0f;

    for (int t = 0; t < 6; ++t) {
        // ---- prefetch next job's cp16 rows (issue early, write late)
        unsigned cpv = 0;
        if (t < 5)
            cpv = *(const unsigned*)((const char*)cp16 + (size_t)(i_base + 2 * (t + 1)) * 512 + tid * 4);

        const char* cb0 = smem + CPB + (t & 1) * 1024 + kh * 16;

        f32x16 acc0 = (f32x16)0.f;
        f32x16 acc1 = (f32x16)0.f;
#pragma unroll
        for (int ks = 0; ks < 16; ++ks) {
            f16x8 cv0 = *(const f16x8*)(cb0 + ks * 32);         // broadcast
            f16x8 cv1 = *(const f16x8*)(cb0 + 512 + ks * 32);   // broadcast
            f16x8 hb0 = __builtin_elementwise_max(rpf[ks] + cv0, zero8);
            f16x8 hb1 = __builtin_elementwise_max(rpf[ks] + cv1, zero8);
            acc0 = __builtin_amdgcn_mfma_f32_32x32x16_f16(w2f[ks], hb0, acc0, 0, 0, 0);
            acc1 = __builtin_amdgcn_mfma_f32_32x32x16_f16(w2f[ks], hb1, acc1, 0, 0, 0);
        }

        // ---- epilogue for both i's: h2 = relu(acc + b2); partial Wf-dot
#pragma unroll
        for (int ii = 0; ii < 2; ++ii) {
            const f32x16& acc = ii ? acc1 : acc0;
            f32x2 P0 = {0.f, 0.f}, P1 = {0.f, 0.f};
#pragma unroll
            for (int q = 0; q < 8; ++q) {
                int idx = kh * 32 + q * 4 + nh;
                f32x4 w01 = *(const f32x4*)(smem + WFT + idx * 16);
                f32x2 bb  = *(const f32x2*)(smem + B2T + idx * 8);
                f32x2 s = {acc[2 * q], acc[2 * q + 1]};
                s = relu2(pk_add(s, bb));
                P0 = pk_fma(lo2(w01), s, P0);
                P1 = pk_fma(hi2(w01), s, P1);
            }
            float p0 = P0[0] + P0[1], p1 = P1[0] + P1[1];
            p0 += __shfl_xor(p0, 32);
            p1 += __shfl_xor(p1, 32);
            if (kh == 0)
                *(f32x2*)(smem + CB + (t & 1) * 2048 + ii * 1024 + nh * 256 + ln * 8)
                    = (f32x2){p0, p1};
        }

        // ---- write prefetched cp16 (latency hidden under K-loop + epilogue)
        if (t < 5)
            *(unsigned*)(smem + CPB + ((t + 1) & 1) * 1024 + tid * 4) = cpv;

        __syncthreads();

        // ---- rotating combiner: wave (t&3); lane's kh picks which i
        if (nh == (t & 3)) {
            const char* cbse = smem + CB + (t & 1) * 2048 + kh * 1024 + ln * 8;
            f32x2 a0 = *(const f32x2*)(cbse);
            f32x2 a1 = *(const f32x2*)(cbse + 256);
            f32x2 a2 = *(const f32x2*)(cbse + 512);
            f32x2 a3 = *(const f32x2*)(cbse + 768);
            float o0 = a0[0] + a1[0] + a2[0] + a3[0] + bf0;
            float o1 = a0[1] + a1[1] + a2[1] + a3[1] + bf1;
            const int i = i_base + 2 * t + kh;
            *(f32x2*)(out + ((size_t)i * NCELL + j0 + ln) * 2) = (f32x2){o0, o1};
        }
    }
}

// ---------------------------------------------------------------- launcher
extern "C" void kernel_launch(void* const* d_in, const int* in_sizes, int n_in,
                              void* d_out, int out_size, void* d_ws, size_t ws_size,
                              hipStream_t stream) {
    const float* z   = (const float*)d_in[0];
    const float* W1  = (const float*)d_in[1];
    const float* b1  = (const float*)d_in[2];
    const float* W2  = (const float*)d_in[3];
    const float* b2  = (const float*)d_in[4];
    const float* Wf  = (const float*)d_in[5];
    const float* bfv = (const float*)d_in[6];
    float* out = (float*)d_out;

    _Float16* rp16 = (_Float16*)d_ws;                 // 768*256 f16
    _Float16* cp16 = rp16 + NCELL * C1;               // 768*256 f16
    _Float16* w2h  = cp16 + NCELL * C1;               // 128*256 f16

    prep_all<<<192 + 128, 256, 0, stream>>>(z, W1, b1, W2, rp16, cp16, w2h);
    pair_head<<<24 * 64, 256, 0, stream>>>(rp16, cp16, w2h, Wf, b2, bfv, out);
}

// Round 10
// 64.042 us; speedup vs baseline: 2.2018x; 1.1576x over previous
//
#include <hip/hip_runtime.h>

// SupNet pair-distance head, v8: 16x16x32 f16 MFMA, 8 independent acc chains
// per wave-job, barrier-free main loop (cp fully pre-staged, partials to
// private CB slots, single final combine).
//   rp16[j][c] = f16( z[j]·W1[c,:128] + b1[c] )
//   cp16[i][c] = f16( z[i]·W1[c,128:] )
//   h[m][c]  = relu(rp16 + cp16)            (f16 math)
//   h2[n][m] = relu( W2[n][:]·h[m][:] + b2[n] )
//   out[m][o]= Wf[o][:]·h2[:][m] + bf[o]
//
// 4 waves/block (wave nh owns 32 n-channels), job = 2 i x 32 j,
// chains = 2ng x 2ii x 2jh = 8 of length 8. ~200 VGPR -> 2 waves/SIMD.

typedef __attribute__((ext_vector_type(8)))  _Float16 f16x8;
typedef __attribute__((ext_vector_type(2)))  float    f32x2;
typedef __attribute__((ext_vector_type(4)))  float    f32x4;

#define NCELL 768
#define DIM   128
#define C1    256
#define C2    128

// LDS map (bytes)
#define CPL    0          // 12 rows * 512B cp16
#define TAB    6144       // 128 * 16B {b2, Wf0, Wf1, 0}
#define CBo    8192       // 384 pairs * 4 nh * 8B partials
#define LDS_SZ 20480

#define MFMA16(a, b, c) __builtin_amdgcn_mfma_f32_16x16x32_f16(a, b, c, 0, 0, 0)

// ---------------------------------------------------------------- fused prep
// blocks 0..191: rp16/cp16 for 4 j's each; blocks 192..319: W2 -> f16.
__global__ __launch_bounds__(256) void prep_all(const float* __restrict__ z,
                                                const float* __restrict__ W1,
                                                const float* __restrict__ b1,
                                                const float* __restrict__ W2,
                                                _Float16* __restrict__ rp16,
                                                _Float16* __restrict__ cp16,
                                                _Float16* __restrict__ w2h) {
    const int tid = threadIdx.x;
    if (blockIdx.x < 192) {
        const int jb4 = blockIdx.x * 4;
        __shared__ float zl[4 * DIM];
        zl[tid]       = z[(size_t)jb4 * DIM + tid];
        zl[tid + 256] = z[(size_t)jb4 * DIM + tid + 256];
        __syncthreads();
        const int o = tid;
        float a1[4] = {0.f, 0.f, 0.f, 0.f};
        float a2[4] = {0.f, 0.f, 0.f, 0.f};
        const f32x4* w4 = (const f32x4*)(W1 + (size_t)o * (2 * DIM));
#pragma unroll 4
        for (int d4 = 0; d4 < 32; ++d4) {
            f32x4 wa = w4[d4], wb = w4[32 + d4];
#pragma unroll
            for (int jj = 0; jj < 4; ++jj) {
                f32x4 zv = *(const f32x4*)(zl + jj * DIM + d4 * 4);
#pragma unroll
                for (int e = 0; e < 4; ++e) {
                    a1[jj] = fmaf(zv[e], wa[e], a1[jj]);
                    a2[jj] = fmaf(zv[e], wb[e], a2[jj]);
                }
            }
        }
        const float bb = b1[o];
#pragma unroll
        for (int jj = 0; jj < 4; ++jj) {
            rp16[(size_t)(jb4 + jj) * C1 + o] = (_Float16)(a1[jj] + bb);
            cp16[(size_t)(jb4 + jj) * C1 + o] = (_Float16)a2[jj];
        }
    } else {
        const int t = (blockIdx.x - 192) * 256 + tid;   // 0..32767
        w2h[t] = (_Float16)W2[t];
    }
}

// ---------------------------------------------------------------- main kernel
// grid = 24 jb-groups * 64 i-chunks = 1536 blocks * 256 thr; 6 jobs * 2 i.
__global__ __launch_bounds__(256, 2) void pair_head(const _Float16* __restrict__ rp16,
                                                    const _Float16* __restrict__ cp16,
                                                    const _Float16* __restrict__ w2h,
                                                    const float* __restrict__ Wf,
                                                    const float* __restrict__ b2,
                                                    const float* __restrict__ bfv,
                                                    float* __restrict__ out) {
    __shared__ char smem[LDS_SZ];
    const int tid = threadIdx.x;
    const int nh  = tid >> 6;      // wave id = n-quarter
    const int l   = tid & 63;
    const int lc  = l & 15;        // fragment col/row index
    const int lg  = l >> 4;        // k-group 0..3
    const int jbg = blockIdx.x >> 6;     // 0..23
    const int ic  = blockIdx.x & 63;     // 0..63
    const int j0  = jbg * 32;
    const int i_base = ic * 12;

    // ---- stage all 12 cp rows (6 KB) once
#pragma unroll
    for (int q = 0; q < 6; ++q) {
        int off = q * 256 + tid;   // u32 index, 1536 total
        ((unsigned*)(smem + CPL))[off] =
            ((const unsigned*)(cp16 + (size_t)i_base * C1))[off];
    }
    // ---- channel table: {b2[n], Wf[0][n], Wf[1][n], 0}
    if (tid < 128) {
        f32x4 e = {b2[tid], Wf[tid], Wf[C2 + tid], 0.f};
        *(f32x4*)(smem + TAB + tid * 16) = e;
    }

    // ---- rp B-fragments in registers (64 VGPRs), constant over all jobs
    f16x8 rpf[2][8];
#pragma unroll
    for (int jh = 0; jh < 2; ++jh)
#pragma unroll
        for (int ks = 0; ks < 8; ++ks)
            rpf[jh][ks] = *(const f16x8*)(rp16 + (size_t)(j0 + jh * 16 + lc) * C1 + lg * 8 + ks * 32);

    // ---- W2 A-fragments for this wave's 32 n-channels (64 VGPRs)
    f16x8 w2f[2][8];
#pragma unroll
    for (int ng = 0; ng < 2; ++ng)
#pragma unroll
        for (int ks = 0; ks < 8; ++ks)
            w2f[ng][ks] = *(const f16x8*)(w2h + (size_t)(nh * 32 + ng * 16 + lc) * C1 + lg * 8 + ks * 32);

    __syncthreads();

    const f16x8 z8 = (f16x8)(_Float16)0.0f;

    for (int t = 0; t < 6; ++t) {
        const char* c0 = smem + CPL + (2 * t) * 512 + lg * 16;

        f32x4 a000 = (f32x4)0.f, a001 = (f32x4)0.f, a010 = (f32x4)0.f, a011 = (f32x4)0.f;
        f32x4 a100 = (f32x4)0.f, a101 = (f32x4)0.f, a110 = (f32x4)0.f, a111 = (f32x4)0.f;

#pragma unroll
        for (int ks = 0; ks < 8; ++ks) {
            f16x8 cv0 = *(const f16x8*)(c0 + ks * 64);          // i = 2t
            f16x8 cv1 = *(const f16x8*)(c0 + 512 + ks * 64);    // i = 2t+1
            f16x8 hb00 = __builtin_elementwise_max(rpf[0][ks] + cv0, z8);  // ii0 jh0
            f16x8 hb01 = __builtin_elementwise_max(rpf[1][ks] + cv0, z8);  // ii0 jh1
            f16x8 hb10 = __builtin_elementwise_max(rpf[0][ks] + cv1, z8);  // ii1 jh0
            f16x8 hb11 = __builtin_elementwise_max(rpf[1][ks] + cv1, z8);  // ii1 jh1
            a000 = MFMA16(w2f[0][ks], hb00, a000);
            a001 = MFMA16(w2f[0][ks], hb01, a001);
            a010 = MFMA16(w2f[0][ks], hb10, a010);
            a011 = MFMA16(w2f[0][ks], hb11, a011);
            a100 = MFMA16(w2f[1][ks], hb00, a100);
            a101 = MFMA16(w2f[1][ks], hb01, a101);
            a110 = MFMA16(w2f[1][ks], hb10, a110);
            a111 = MFMA16(w2f[1][ks], hb11, a111);
        }

        // ---- epilogue: h2 = relu(acc + b2); partial Wf-dot over 32 channels
        f32x2 P00 = {0.f, 0.f}, P01 = {0.f, 0.f}, P10 = {0.f, 0.f}, P11 = {0.f, 0.f};
#pragma unroll
        for (int ng = 0; ng < 2; ++ng) {
#pragma unroll
            for (int r = 0; r < 4; ++r) {
                int n = nh * 32 + ng * 16 + lg * 4 + r;
                f32x4 e = *(const f32x4*)(smem + TAB + n * 16);  // {b2, wf0, wf1}
                f32x4 q00 = ng ? a100 : a000, q01 = ng ? a101 : a001;
                f32x4 q10 = ng ? a110 : a010, q11 = ng ? a111 : a011;
                float h;
                h = fmaxf(q00[r] + e[0], 0.f); P00[0] = fmaf(e[1], h, P00[0]); P00[1] = fmaf(e[2], h, P00[1]);
                h = fmaxf(q01[r] + e[0], 0.f); P01[0] = fmaf(e[1], h, P01[0]); P01[1] = fmaf(e[2], h, P01[1]);
                h = fmaxf(q10[r] + e[0], 0.f); P10[0] = fmaf(e[1], h, P10[0]); P10[1] = fmaf(e[2], h, P10[1]);
                h = fmaxf(q11[r] + e[0], 0.f); P11[0] = fmaf(e[1], h, P11[0]); P11[1] = fmaf(e[2], h, P11[1]);
            }
        }
        // reduce over the 4 lane-groups (same pair col c = l&15)
#pragma unroll
        for (int d = 16; d <= 32; d <<= 1) {
            P00[0] += __shfl_xor(P00[0], d); P00[1] += __shfl_xor(P00[1], d);
            P01[0] += __shfl_xor(P01[0], d); P01[1] += __shfl_xor(P01[1], d);
            P10[0] += __shfl_xor(P10[0], d); P10[1] += __shfl_xor(P10[1], d);
            P11[0] += __shfl_xor(P11[0], d); P11[1] += __shfl_xor(P11[1], d);
        }
        if (l < 16) {
            // pair index p = t*64 + ii*32 + jh*16 + c ; slot = p*32 + nh*8
            char* cb = smem + CBo + (size_t)(t * 64 + l) * 32 + nh * 8;
            *(f32x2*)(cb)           = P00;   // ii0 jh0
            *(f32x2*)(cb + 16 * 32) = P01;   // ii0 jh1
            *(f32x2*)(cb + 32 * 32) = P10;   // ii1 jh0
            *(f32x2*)(cb + 48 * 32) = P11;   // ii1 jh1
        }
    }

    __syncthreads();

    // ---- final combine: 384 pairs, sum the 4 n-quarter partials
    const float bf0 = bfv[0], bf1 = bfv[1];
#pragma unroll
    for (int p = tid; p < 384; p += 256) {
        const char* cb = smem + CBo + (size_t)p * 32;
        f32x2 a0 = *(const f32x2*)(cb);
        f32x2 a1 = *(const f32x2*)(cb + 8);
        f32x2 a2 = *(const f32x2*)(cb + 16);
        f32x2 a3 = *(const f32x2*)(cb + 24);
        float o0 = a0[0] + a1[0] + a2[0] + a3[0] + bf0;
        float o1 = a0[1] + a1[1] + a2[1] + a3[1] + bf1;
        int c = p & 15, jh = (p >> 4) & 1, ii = (p >> 5) & 1, t = p >> 6;
        int i = i_base + 2 * t + ii;
        int j = j0 + jh * 16 + c;
        *(f32x2*)(out + ((size_t)i * NCELL + j) * 2) = (f32x2){o0, o1};
    }
}

// ---------------------------------------------------------------- launcher
extern "C" void kernel_launch(void* const* d_in, const int* in_sizes, int n_in,
                              void* d_out, int out_size, void* d_ws, size_t ws_size,
                              hipStream_t stream) {
    const float* z   = (const float*)d_in[0];
    const float* W1  = (const float*)d_in[1];
    const float* b1  = (const float*)d_in[2];
    const float* W2  = (const float*)d_in[3];
    const float* b2  = (const float*)d_in[4];
    const float* Wf  = (const float*)d_in[5];
    const float* bfv = (const float*)d_in[6];
    float* out = (float*)d_out;

    _Float16* rp16 = (_Float16*)d_ws;                 // 768*256 f16
    _Float16* cp16 = rp16 + NCELL * C1;               // 768*256 f16
    _Float16* w2h  = cp16 + NCELL * C1;               // 128*256 f16

    prep_all<<<192 + 128, 256, 0, stream>>>(z, W1, b1, W2, rp16, cp16, w2h);
    pair_head<<<24 * 64, 256, 0, stream>>>(rp16, cp16, w2h, Wf, b2, bfv, out);
}